// Round 4
// baseline (76.028 us; speedup 1.0000x reference)
//
#include <hip/hip_runtime.h>

#define NN 2048
#define KK 32

// workspace layout (bytes):
//  u_pk   : [2048 j][32 b][32 k][8 zp] u32 (bf16 z-pairs)  64 MiB @ 0   (j-major!)
//  t_part2: [32 b][8 sl][512] f32                         512 KiB @ 67108864
//  t      : [32 b][32 k][16 z] f32                         64 KiB @ 67633152
//  s_part : [32 b][64 jc][512] f32                          4 MiB @ 67698688
#define WS_U     0
#define WS_TP2   67108864UL
#define WS_T     67633152UL
#define WS_SPART 67698688UL
#define WS_NEED  71892992UL

__device__ __forceinline__ float bf_lo(unsigned v) { return __uint_as_float(v << 16); }
__device__ __forceinline__ float bf_hi(unsigned v) { return __uint_as_float(v & 0xffff0000u); }
__device__ __forceinline__ unsigned pack_bf16(float a, float b) {
    unsigned ua = __float_as_uint(a), ub = __float_as_uint(b);
    return ((ua + 0x8000u) >> 16) | ((ub + 0x8000u) & 0xffff0000u);
}

// ---------------- K1: pure projection u = x @ w (bf16 packed, j-major) ------
// grid 2048 (one j per block), block 128: k = tid>>2, zq = tid&3.
// w slice: 16 x dwordx4 per thread (256B, independent, issued upfront).
// x rows: wave-uniform addresses -> scalar loads (no LDS, no barrier).
// u store: per b, block writes one contiguous 1 KiB row; whole grid streams
// u sequentially (64 MiB linear write).
__global__ __launch_bounds__(128)
void k1_u(const float* __restrict__ x, const float* __restrict__ w,
          unsigned* __restrict__ u_pk)
{
    const int tid = threadIdx.x;
    const int zq  = tid & 3;
    const int k   = tid >> 2;
    const int j   = blockIdx.x;

    // w[k][j][i][4zq .. 4zq+3], i = 0..15 (each element read exactly once)
    const float4* w4 = reinterpret_cast<const float4*>(
        w + (((size_t)k * NN + j) * 16) * 16) + zq;
    float4 wr[16];
#pragma unroll
    for (int i = 0; i < 16; ++i) wr[i] = w4[i * 4];

    unsigned* __restrict__ ub = u_pk + (size_t)j * 8192 + k * 8 + zq * 2;
#pragma unroll 4
    for (int b = 0; b < 32; ++b) {
        const float* __restrict__ xr = x + ((size_t)b * NN + j) * 16; // uniform -> s_load
        float xs[16];
#pragma unroll
        for (int i = 0; i < 16; ++i) xs[i] = xr[i];
        float4 acc = make_float4(0.f, 0.f, 0.f, 0.f);
#pragma unroll
        for (int i = 0; i < 16; ++i) {
            acc.x = fmaf(xs[i], wr[i].x, acc.x);
            acc.y = fmaf(xs[i], wr[i].y, acc.y);
            acc.z = fmaf(xs[i], wr[i].z, acc.z);
            acc.w = fmaf(xs[i], wr[i].w, acc.w);
        }
        uint2 o;
        o.x = pack_bf16(acc.x, acc.y);
        o.y = pack_bf16(acc.z, acc.w);
        *reinterpret_cast<uint2*>(ub + (size_t)b * 256) = o;
    }
}

// ---------------- K2a: t partials = sum over j-slices of u (uint4 loads) ----
// grid 256 (= 32 b * 8 slices), block 1024: js = tid>>6 (16), sl64 = tid&63.
__global__ __launch_bounds__(1024)
void k2a_tpart(const unsigned* __restrict__ u_pk, float* __restrict__ t_part2)
{
    __shared__ float red[16][64][8];
    const int tid  = threadIdx.x;
    const int js   = tid >> 6;
    const int sl64 = tid & 63;            // uint4 slot within (j,b) row
    const int b    = blockIdx.x >> 3;
    const int slj  = blockIdx.x & 7;

    // j = slj*256 + it*16 + js ; u row at [(j*32 + b)*64] uint4s
    const uint4* up = reinterpret_cast<const uint4*>(u_pk)
                    + ((size_t)(slj * 256 + js) * 32 + b) * 64 + sl64;
    float a[8];
#pragma unroll
    for (int e = 0; e < 8; ++e) a[e] = 0.f;
#pragma unroll
    for (int it = 0; it < 16; ++it) {
        uint4 v = up[(size_t)it * (16 * 32 * 64)];
        a[0] += bf_lo(v.x); a[1] += bf_hi(v.x);
        a[2] += bf_lo(v.y); a[3] += bf_hi(v.y);
        a[4] += bf_lo(v.z); a[5] += bf_hi(v.z);
        a[6] += bf_lo(v.w); a[7] += bf_hi(v.w);
    }
#pragma unroll
    for (int e = 0; e < 8; ++e) red[js][sl64][e] = a[e];
    __syncthreads();
    if (tid < 512) {
        const int s = tid >> 3, e = tid & 7;
        float acc = 0.f;
#pragma unroll
        for (int r = 0; r < 16; ++r) acc += red[r][s][e];
        t_part2[((size_t)b * 8 + slj) * 512 + s * 8 + e] = acc;
    }
}

// ---------------- K2a2: reduce 8 slices -> t (float4) -----------------------
__global__ __launch_bounds__(256)
void k2a2_t(const float* __restrict__ t_part2, float* __restrict__ t)
{
    const int idx4 = blockIdx.x * 256 + threadIdx.x;   // 4096 float4s
    const int b = idx4 >> 7, loc4 = idx4 & 127;
    const float4* p = reinterpret_cast<const float4*>(t_part2) + (size_t)b * 1024 + loc4;
    float4 s = make_float4(0.f, 0.f, 0.f, 0.f);
#pragma unroll
    for (int sl = 0; sl < 8; ++sl) {
        float4 v = p[sl * 128];
        s.x += v.x; s.y += v.y; s.z += v.z; s.w += v.w;
    }
    reinterpret_cast<float4*>(t)[idx4] = s;
}

// ---------------- K2b: logits + softmax + bias + s-partials (fused) ---------
// grid 2048 (= 32 b * 64 j-chunks of 32), block 256: k = tid&31, jl = tid>>5.
__global__ __launch_bounds__(256)
void k2b_fused(const unsigned* __restrict__ u_pk, const float* __restrict__ t,
               const float* __restrict__ bias, float* __restrict__ s_part)
{
    __shared__ float lc_lds[32][33];
    __shared__ float s_lds[8][32][16];
    const int tid = threadIdx.x;
    const int k   = tid & 31;
    const int jl  = tid >> 5;
    const int b   = blockIdx.x >> 6;
    const int jc  = blockIdx.x & 63;

    float tr[16];
    const float4* tp = reinterpret_cast<const float4*>(t + ((size_t)b * KK + k) * 16);
#pragma unroll
    for (int q = 0; q < 4; ++q) {
        float4 v = tp[q];
        tr[4 * q + 0] = v.x; tr[4 * q + 1] = v.y; tr[4 * q + 2] = v.z; tr[4 * q + 3] = v.w;
    }

    uint4 ua[4], ud[4];
#pragma unroll
    for (int jj = 0; jj < 4; ++jj) {
        const int jL = jj * 8 + jl;
        const int jg = jc * 32 + jL;
        const uint4* up = reinterpret_cast<const uint4*>(u_pk)
                        + ((size_t)jg * 32 + b) * 64 + k * 2;
        ua[jj] = up[0]; ud[jj] = up[1];
        float a0 = 0.f, a1 = 0.f;
        a0 = fmaf(bf_lo(ua[jj].x), tr[0],  a0); a1 = fmaf(bf_hi(ua[jj].x), tr[1],  a1);
        a0 = fmaf(bf_lo(ua[jj].y), tr[2],  a0); a1 = fmaf(bf_hi(ua[jj].y), tr[3],  a1);
        a0 = fmaf(bf_lo(ua[jj].z), tr[4],  a0); a1 = fmaf(bf_hi(ua[jj].z), tr[5],  a1);
        a0 = fmaf(bf_lo(ua[jj].w), tr[6],  a0); a1 = fmaf(bf_hi(ua[jj].w), tr[7],  a1);
        a0 = fmaf(bf_lo(ud[jj].x), tr[8],  a0); a1 = fmaf(bf_hi(ud[jj].x), tr[9],  a1);
        a0 = fmaf(bf_lo(ud[jj].y), tr[10], a0); a1 = fmaf(bf_hi(ud[jj].y), tr[11], a1);
        a0 = fmaf(bf_lo(ud[jj].z), tr[12], a0); a1 = fmaf(bf_hi(ud[jj].z), tr[13], a1);
        a0 = fmaf(bf_lo(ud[jj].w), tr[14], a0); a1 = fmaf(bf_hi(ud[jj].w), tr[15], a1);
        lc_lds[jL][k] = a0 + a1;
    }
    __syncthreads();

    {
        const int jq = tid >> 3, kq = tid & 7;
        float lv[4];
#pragma unroll
        for (int m = 0; m < 4; ++m) lv[m] = lc_lds[jq][kq * 4 + m];
        float pm = fmaxf(fmaxf(lv[0], lv[1]), fmaxf(lv[2], lv[3]));
        pm = fmaxf(pm, __shfl_xor(pm, 1));
        pm = fmaxf(pm, __shfl_xor(pm, 2));
        pm = fmaxf(pm, __shfl_xor(pm, 4));
        float ev[4], ps = 0.f;
#pragma unroll
        for (int m = 0; m < 4; ++m) { ev[m] = __expf((lv[m] - pm) * 0.25f); ps += ev[m]; }
        ps += __shfl_xor(ps, 1);
        ps += __shfl_xor(ps, 2);
        ps += __shfl_xor(ps, 4);
        const float inv = 1.f / ps;
        const int jg = jc * 32 + jq;
#pragma unroll
        for (int m = 0; m < 4; ++m)
            lv[m] = ev[m] * inv + bias[(size_t)(kq * 4 + m) * NN + jg];
        __syncthreads();
#pragma unroll
        for (int m = 0; m < 4; ++m) lc_lds[jq][kq * 4 + m] = lv[m];
    }
    __syncthreads();

    float sacc[16];
#pragma unroll
    for (int z = 0; z < 16; ++z) sacc[z] = 0.f;
#pragma unroll
    for (int jj = 0; jj < 4; ++jj) {
        const float cv = lc_lds[jj * 8 + jl][k];
        const uint4 a = ua[jj], d = ud[jj];
        sacc[0]  = fmaf(cv, bf_lo(a.x), sacc[0]);  sacc[1]  = fmaf(cv, bf_hi(a.x), sacc[1]);
        sacc[2]  = fmaf(cv, bf_lo(a.y), sacc[2]);  sacc[3]  = fmaf(cv, bf_hi(a.y), sacc[3]);
        sacc[4]  = fmaf(cv, bf_lo(a.z), sacc[4]);  sacc[5]  = fmaf(cv, bf_hi(a.z), sacc[5]);
        sacc[6]  = fmaf(cv, bf_lo(a.w), sacc[6]);  sacc[7]  = fmaf(cv, bf_hi(a.w), sacc[7]);
        sacc[8]  = fmaf(cv, bf_lo(d.x), sacc[8]);  sacc[9]  = fmaf(cv, bf_hi(d.x), sacc[9]);
        sacc[10] = fmaf(cv, bf_lo(d.y), sacc[10]); sacc[11] = fmaf(cv, bf_hi(d.y), sacc[11]);
        sacc[12] = fmaf(cv, bf_lo(d.z), sacc[12]); sacc[13] = fmaf(cv, bf_hi(d.z), sacc[13]);
        sacc[14] = fmaf(cv, bf_lo(d.w), sacc[14]); sacc[15] = fmaf(cv, bf_hi(d.w), sacc[15]);
    }

#pragma unroll
    for (int q = 0; q < 4; ++q)
        *reinterpret_cast<float4*>(&s_lds[jl][k][q * 4]) =
            make_float4(sacc[q * 4], sacc[q * 4 + 1], sacc[q * 4 + 2], sacc[q * 4 + 3]);
    __syncthreads();
    {
        const int kk = tid >> 3, zp = tid & 7;
        float2 o; o.x = 0.f; o.y = 0.f;
#pragma unroll
        for (int l = 0; l < 8; ++l) {
            o.x += s_lds[l][kk][2 * zp];
            o.y += s_lds[l][kk][2 * zp + 1];
        }
        reinterpret_cast<float2*>(s_part)[((size_t)b * 64 + jc) * 256 + kk * 8 + zp] = o;
    }
}

// ---------------- K4: reduce jc slices + squash (float4) --------------------
__global__ __launch_bounds__(256)
void k4_squash(const float* __restrict__ s_part, float* __restrict__ out)
{
    const int idx4 = blockIdx.x * 256 + threadIdx.x;   // 4096 float4s
    const int b = idx4 >> 7, loc4 = idx4 & 127;        // loc4 = k*4 + zq
    const float4* p = reinterpret_cast<const float4*>(s_part) + (size_t)b * 8192 + loc4;
    float4 s = make_float4(0.f, 0.f, 0.f, 0.f);
#pragma unroll 8
    for (int jc = 0; jc < 64; ++jc) {
        float4 v = p[jc * 128];
        s.x += v.x; s.y += v.y; s.z += v.z; s.w += v.w;
    }
    float ss = s.x * s.x + s.y * s.y + s.z * s.z + s.w * s.w;
    ss += __shfl_xor(ss, 1);   // lanes zq 0..3 of same (b,k)
    ss += __shfl_xor(ss, 2);
    const float n = sqrtf(ss);
    const float sc = (1.f - 1.f / (__expf(n) + 1e-20f)) / (n + 1e-20f);
    float4 o; o.x = s.x * sc; o.y = s.y * sc; o.z = s.z * sc; o.w = s.w * sc;
    reinterpret_cast<float4*>(out)[idx4] = o;
}

// sentinel if workspace too small
__global__ void k_sentinel(float* __restrict__ out)
{
    out[blockIdx.x * 256 + threadIdx.x] = 12345.0f;
}

extern "C" void kernel_launch(void* const* d_in, const int* in_sizes, int n_in,
                              void* d_out, int out_size, void* d_ws, size_t ws_size,
                              hipStream_t stream)
{
    const float* x    = (const float*)d_in[0];
    const float* w    = (const float*)d_in[1];
    const float* bias = (const float*)d_in[2];
    float* out        = (float*)d_out;

    char* ws = (char*)d_ws;
    if (ws_size < WS_NEED) {
        k_sentinel<<<dim3(64), dim3(256), 0, stream>>>(out);
        return;
    }
    unsigned* u_pk = (unsigned*)(ws + WS_U);
    float* t_part2 = (float*)(ws + WS_TP2);
    float* t       = (float*)(ws + WS_T);
    float* s_part  = (float*)(ws + WS_SPART);

    k1_u     <<<dim3(2048), dim3(128),  0, stream>>>(x, w, u_pk);
    k2a_tpart<<<dim3(256),  dim3(1024), 0, stream>>>(u_pk, t_part2);
    k2a2_t   <<<dim3(16),   dim3(256),  0, stream>>>(t_part2, t);
    k2b_fused<<<dim3(2048), dim3(256),  0, stream>>>(u_pk, t, bias, s_part);
    k4_squash<<<dim3(16),   dim3(256),  0, stream>>>(s_part, out);
}